// Round 10
// baseline (105.693 us; speedup 1.0000x reference)
//
#include <hip/hip_runtime.h>

#define NPART 4096
#define E_TOT 262144
#define HID   128
#define FDOF  6
#define WE    32                  // edges per wave-tile (2 groups of 16)
#define NWT   (E_TOT / WE)        // 8192 tiles
#define GRID  1024                // x4 waves = 4096 -> 2 tiles/wave exact
#define NW    (GRID * 4)

typedef __bf16 bf16x8 __attribute__((ext_vector_type(8)));
typedef float  f32x4  __attribute__((ext_vector_type(4)));
typedef unsigned int uint32x4 __attribute__((ext_vector_type(4)));
typedef int    i32x2  __attribute__((ext_vector_type(2)));

__global__ void pairvel_zero_kernel(float* __restrict__ out, int n) {
    const int i = blockIdx.x * blockDim.x + threadIdx.x;
    if (i < n) out[i] = 0.0f;
}

static __device__ __forceinline__ unsigned int pack2(float a, float b) {
    const unsigned short ua = __builtin_bit_cast(unsigned short, (__bf16)a);
    const unsigned short ub = __builtin_bit_cast(unsigned short, (__bf16)b);
    return (unsigned int)ua | ((unsigned int)ub << 16);
}

// Round 10: R9 structure with the two stalls the R9 counters exposed fixed:
// (1) inter-layer exchange now uses v_permlane32_swap_b32 (VALU ~4cy) in
// place of __shfl_xor/ds_bpermute (~120cy LDS-latency on the critical
// path; 16 per tile). swap(pe,po) -> r[0]={pe.lo,po.lo}, r[1]={pe.hi,
// po.hi}; w0 = islow?r[0]:r[1], w2 = islow?r[1]:r[0] (matches R9's
// VALIDATED mapping exactly). (2) GRID 512->1024: 4 blocks/CU resident
// (LDS 32KB, VGPR 96 both allow it) -> 16 waves/CU, 2 tiles/wave.
__global__ __launch_bounds__(256) void pairvel_mfma_kernel(
    const float* __restrict__ rel,       // [N,N,3]
    const int*   __restrict__ tgt,       // [E]
    const int*   __restrict__ src,       // [E]
    const float* __restrict__ force,     // [N,6]
    const float* __restrict__ visc,
    const float* __restrict__ medianp,
    const float* __restrict__ contactp,
    const float* __restrict__ W1,        // [19,128]
    const float* __restrict__ b1,        // [128]
    const float* __restrict__ W2,        // [128,128]
    const float* __restrict__ b2,        // [128]
    const float* __restrict__ W3,        // [128,6]
    const float* __restrict__ b3,        // [6]
    float* __restrict__ out)             // [N,6]
{
    const int tid = threadIdx.x;
    const int w   = tid >> 6;
    const int l   = tid & 63;
    const int l15 = l & 15;
    const int lhi = l >> 4;
    const bool islow = (l < 32);

    __shared__ __align__(16) __bf16 W2L[4][8][64][8];   // 32 KB

    // ---- stage W2 as A-frags with permuted k-rows --------------------------
    #pragma unroll
    for (int i = 0; i < 8; ++i) {
        const int entry = i * 256 + tid;        // 0..2047
        const int kt = entry >> 9;
        const int nb = (entry >> 6) & 7;
        const int ln = entry & 63;
        const int sl15 = ln & 15, slhi = ln >> 4;
        const int base1 = (slhi & 1) * 4 + (slhi & 2) * 12;    // 0,4,24,28
        const int base2 = 8 + (slhi & 1) * 4 + (slhi & 2) * 4; // 8,12,16,20
        bf16x8 v;
        #pragma unroll
        for (int r = 0; r < 8; ++r) {
            const int row = kt * 32 + ((r < 4) ? (base1 + r) : (base2 + r - 4));
            v[r] = (__bf16)W2[row * HID + nb * 16 + sl15];
        }
        *reinterpret_cast<bf16x8*>(&W2L[kt][nb][ln][0]) = v;
    }

    // ---- W1 A-frags (identity k-order; k=31 slot carries b1) ---------------
    bf16x8 w1A[8];
    #pragma unroll
    for (int nb = 0; nb < 8; ++nb)
        #pragma unroll
        for (int r = 0; r < 8; ++r) {
            const int c = lhi * 8 + r;
            float v = 0.0f;
            if (c < 19) { const int ko = (c < 12) ? c + 7 : c - 12;
                          v = W1[ko * HID + nb * 16 + l15]; }
            else if (c == 31) v = b1[nb * 16 + l15];
            w1A[nb][r] = (__bf16)v;
        }

    // ---- W3 A-frags (permuted k-rows matching the exchange) ----------------
    const int base1 = (lhi & 1) * 4 + (lhi & 2) * 12;
    const int base2 = 8 + (lhi & 1) * 4 + (lhi & 2) * 4;
    bf16x8 w3A[4];
    #pragma unroll
    for (int kt = 0; kt < 4; ++kt)
        #pragma unroll
        for (int r = 0; r < 8; ++r) {
            const int row = kt * 32 + ((r < 4) ? (base1 + r) : (base2 + r - 4));
            w3A[kt][r] = (l15 < FDOF) ? (__bf16)W3[row * FDOF + l15]
                                      : (__bf16)0.0f;
        }

    // ---- biases ------------------------------------------------------------
    f32x4 b2i[8];
    #pragma unroll
    for (int nb = 0; nb < 8; ++nb)
        b2i[nb] = *reinterpret_cast<const f32x4*>(&b2[nb * 16 + lhi * 4]);
    float b3i[4];
    #pragma unroll
    for (int r = 0; r < 4; ++r) {
        const int d = lhi * 4 + r;
        b3i[r] = (d < FDOF) ? b3[d] : 0.0f;
    }
    const float inv_mu  = 1.0f / visc[0];
    const float median  = medianp[0];
    const float contact = contactp[0];

    __syncthreads();   // W2L ready (only barrier)

    // ---- per-lane raw gather state (role-dependent) ------------------------
    int   pft[2];
    float pf[2][8];

    auto gather_issue = [&](int tile) {
        #pragma unroll
        for (int g = 0; g < 2; ++g) {
            if (lhi < 3) {
                const int eg = tile * WE + g * 16 + l15;
                const int tg = tgt[eg];
                const int sg = src[eg];
                pft[g] = tg;
                if (lhi == 0) {
                    const float2* ft = (const float2*)(force + tg * FDOF);
                    const float2* fs = (const float2*)(force + sg * FDOF);
                    const float2 a = ft[0], b = ft[1], c = ft[2], d = fs[0];
                    pf[g][0] = a.x; pf[g][1] = a.y; pf[g][2] = b.x;
                    pf[g][3] = b.y; pf[g][4] = c.x; pf[g][5] = c.y;
                    pf[g][6] = d.x; pf[g][7] = d.y;
                } else if (lhi == 1) {
                    const float2* fs = (const float2*)(force + sg * FDOF);
                    const float2 a = fs[1], b = fs[2];
                    const float* rp = rel + ((size_t)tg * NPART + sg) * 3;
                    pf[g][0] = a.x;  pf[g][1] = a.y;
                    pf[g][2] = b.x;  pf[g][3] = b.y;
                    pf[g][4] = rp[0]; pf[g][5] = rp[1]; pf[g][6] = rp[2];
                } else {
                    const float* rp = rel + ((size_t)tg * NPART + sg) * 3;
                    pf[g][0] = rp[0]; pf[g][1] = rp[1]; pf[g][2] = rp[2];
                }
            }
        }
    };

    auto build_xb = [&](int g) -> bf16x8 {
        float x0=0,x1=0,x2=0,x3=0,x4=0,x5=0,x6=0,x7=0;
        if (lhi == 0) {
            x0=pf[g][0]; x1=pf[g][1]; x2=pf[g][2]; x3=pf[g][3];
            x4=pf[g][4]; x5=pf[g][5]; x6=pf[g][6]; x7=pf[g][7];
        } else if (lhi == 1) {
            x0=pf[g][0]; x1=pf[g][1]; x2=pf[g][2]; x3=pf[g][3];
            const float r0=pf[g][4], r1=pf[g][5], r2=pf[g][6];
            const float dist = fmaxf(sqrtf(r0*r0+r1*r1+r2*r2), 1e-8f);
            x4=r0; x5=r1; x6=r2; x7=dist;
        } else if (lhi == 2) {
            const float r0=pf[g][0], r1=pf[g][1], r2=pf[g][2];
            const float dist = fmaxf(sqrtf(r0*r0+r1*r1+r2*r2), 1e-8f);
            const float rsh = dist - median;
            const float rs  = rsh * rsh;
            x0=rs; x1=rs*rs; x2=dist-contact;
        } else {
            x7 = 1.0f;   // bias feature (k=31)
        }
        return (bf16x8){ (__bf16)x0,(__bf16)x1,(__bf16)x2,(__bf16)x3,
                         (__bf16)x4,(__bf16)x5,(__bf16)x6,(__bf16)x7 };
    };

    // VALU-only half-exchange: swap(pe,po) -> r[0]={pe.lo,po.lo},
    // r[1]={pe.hi,po.hi};  w_own = islow?r[0]:r[1], w_other = islow?r[1]:r[0]
    auto exchange = [&](unsigned pe_lo, unsigned pe_hi,
                        unsigned po_lo, unsigned po_hi) -> bf16x8 {
        const i32x2 r0 = __builtin_amdgcn_permlane32_swap(
            (int)pe_lo, (int)po_lo, false, false);
        const i32x2 r1 = __builtin_amdgcn_permlane32_swap(
            (int)pe_hi, (int)po_hi, false, false);
        const unsigned w0 = (unsigned)(islow ? r0[0] : r0[1]);
        const unsigned w1 = (unsigned)(islow ? r1[0] : r1[1]);
        const unsigned w2 = (unsigned)(islow ? r0[1] : r0[0]);
        const unsigned w3 = (unsigned)(islow ? r1[1] : r1[0]);
        return __builtin_bit_cast(bf16x8, (uint32x4){w0, w1, w2, w3});
    };

    const int gw = blockIdx.x * 4 + w;
    gather_issue(gw);

    for (int tile = gw; tile < NWT; tile += NW) {
        // ---- consume raw -> X B-frags; save targets; issue next prefetch ---
        const bf16x8 xb0 = build_xb(0);
        const bf16x8 xb1 = build_xb(1);
        const int tga0 = pft[0], tga1 = pft[1];
        if (tile + NW < NWT) gather_issue(tile + NW);

        // ---- layer 1: 16 MFMA, bias via k=31 -------------------------------
        bf16x8 h1b[2][4];
        #pragma unroll
        for (int q = 0; q < 4; ++q) {
            unsigned pe_lo[2], pe_hi[2], po_lo[2], po_hi[2];
            #pragma unroll
            for (int par = 0; par < 2; ++par) {
                const int nb = 2 * q + par;
                #pragma unroll
                for (int g = 0; g < 2; ++g) {
                    f32x4 acc = {0.f, 0.f, 0.f, 0.f};
                    acc = __builtin_amdgcn_mfma_f32_16x16x32_bf16(
                              w1A[nb], g ? xb1 : xb0, acc, 0, 0, 0);
                    const unsigned lo = pack2(fmaxf(acc[0],0.f), fmaxf(acc[1],0.f));
                    const unsigned hi = pack2(fmaxf(acc[2],0.f), fmaxf(acc[3],0.f));
                    if (par == 0) { pe_lo[g] = lo; pe_hi[g] = hi; }
                    else          { po_lo[g] = lo; po_hi[g] = hi; }
                }
            }
            #pragma unroll
            for (int g = 0; g < 2; ++g)
                h1b[g][q] = exchange(pe_lo[g], pe_hi[g], po_lo[g], po_hi[g]);
        }

        // ---- layer 2: 32 LDS b128 reads + 64 MFMA --------------------------
        bf16x8 h2b[2][4];
        #pragma unroll
        for (int q = 0; q < 4; ++q) {
            unsigned pe_lo[2], pe_hi[2], po_lo[2], po_hi[2];
            #pragma unroll
            for (int par = 0; par < 2; ++par) {
                const int nb = 2 * q + par;
                f32x4 acc0 = b2i[nb];
                f32x4 acc1 = b2i[nb];
                #pragma unroll
                for (int kt = 0; kt < 4; ++kt) {
                    const bf16x8 wa = *reinterpret_cast<const bf16x8*>(
                        &W2L[kt][nb][l][0]);
                    acc0 = __builtin_amdgcn_mfma_f32_16x16x32_bf16(
                               wa, h1b[0][kt], acc0, 0, 0, 0);
                    acc1 = __builtin_amdgcn_mfma_f32_16x16x32_bf16(
                               wa, h1b[1][kt], acc1, 0, 0, 0);
                }
                const unsigned lo0 = pack2(fmaxf(acc0[0],0.f), fmaxf(acc0[1],0.f));
                const unsigned hi0 = pack2(fmaxf(acc0[2],0.f), fmaxf(acc0[3],0.f));
                const unsigned lo1 = pack2(fmaxf(acc1[0],0.f), fmaxf(acc1[1],0.f));
                const unsigned hi1 = pack2(fmaxf(acc1[2],0.f), fmaxf(acc1[3],0.f));
                if (par == 0) { pe_lo[0]=lo0; pe_hi[0]=hi0; pe_lo[1]=lo1; pe_hi[1]=hi1; }
                else          { po_lo[0]=lo0; po_hi[0]=hi0; po_lo[1]=lo1; po_hi[1]=hi1; }
            }
            #pragma unroll
            for (int g = 0; g < 2; ++g)
                h2b[g][q] = exchange(pe_lo[g], pe_hi[g], po_lo[g], po_hi[g]);
        }

        // ---- layer 3: 8 MFMA ------------------------------------------------
        f32x4 acc30 = {0.f,0.f,0.f,0.f}, acc31 = {0.f,0.f,0.f,0.f};
        #pragma unroll
        for (int kt = 0; kt < 4; ++kt) {
            acc30 = __builtin_amdgcn_mfma_f32_16x16x32_bf16(
                        w3A[kt], h2b[0][kt], acc30, 0, 0, 0);
            acc31 = __builtin_amdgcn_mfma_f32_16x16x32_bf16(
                        w3A[kt], h2b[1][kt], acc31, 0, 0, 0);
        }

        // ---- scatter: lanes lhi0 (dof 0-3), lhi1 (dof 4,5) -----------------
        if (lhi < 2) {
            #pragma unroll
            for (int j = 0; j < 4; ++j) {
                const int d = lhi * 4 + j;
                if (d < FDOF) {
                    atomicAdd(&out[(size_t)tga0 * FDOF + d],
                              (acc30[j] + b3i[j]) * inv_mu);
                    atomicAdd(&out[(size_t)tga1 * FDOF + d],
                              (acc31[j] + b3i[j]) * inv_mu);
                }
            }
        }
    }
}

extern "C" void kernel_launch(void* const* d_in, const int* in_sizes, int n_in,
                              void* d_out, int out_size, void* d_ws, size_t ws_size,
                              hipStream_t stream) {
    const float* rel   = (const float*)d_in[0];
    const int*   tgt   = (const int*)d_in[1];
    const int*   src   = (const int*)d_in[2];
    const float* force = (const float*)d_in[3];
    const float* visc  = (const float*)d_in[4];
    const float* med   = (const float*)d_in[5];
    const float* con   = (const float*)d_in[6];
    const float* W1    = (const float*)d_in[7];
    const float* b1    = (const float*)d_in[8];
    const float* W2    = (const float*)d_in[9];
    const float* b2    = (const float*)d_in[10];
    const float* W3    = (const float*)d_in[11];
    const float* b3    = (const float*)d_in[12];
    float* out = (float*)d_out;

    pairvel_zero_kernel<<<(out_size + 255) / 256, 256, 0, stream>>>(out, out_size);
    pairvel_mfma_kernel<<<GRID, 256, 0, stream>>>(
        rel, tgt, src, force, visc, med, con, W1, b1, W2, b2, W3, b3, out);
}

// Round 11
// 50.733 us; speedup vs baseline: 2.0833x; 2.0833x over previous
//
#include <hip/hip_runtime.h>

#define NPART 4096
#define E_TOT 262144
#define HID   128
#define FDOF  6
#define BM    64                 // edges per block-iteration
#define NIT   (E_TOT / BM)       // 4096
#define GRID  1024               // 4 iters/block exactly (balanced)
#define XPAD  40                 // 80 B rows
#define HPAD  136                // 272 B rows
#define NCOPY 8                  // partial output copies (atomic spreading)
#define OUTSZ (NPART * FDOF)     // 24576

typedef __bf16 bf16x8 __attribute__((ext_vector_type(8)));
typedef float  f32x4  __attribute__((ext_vector_type(4)));

__global__ void pairvel_zero_kernel(float* __restrict__ p, int n) {
    const int i = blockIdx.x * blockDim.x + threadIdx.x;
    if (i < n) p[i] = 0.0f;
}

// out[i] = sum over the NCOPY partial buffers (overwrites out; no out zeroing)
__global__ void pairvel_reduce_kernel(const float* __restrict__ wsp,
                                      float* __restrict__ out) {
    const int i = blockIdx.x * blockDim.x + threadIdx.x;
    if (i < OUTSZ) {
        float s = 0.0f;
        #pragma unroll
        for (int c = 0; c < NCOPY; ++c) s += wsp[c * OUTSZ + i];
        out[i] = s;
    }
}

// Round 11: R6 kernel body UNCHANGED except the scatter target: atomics go
// to one of NCOPY=8 partial buffers in d_ws (block b -> copy b&7), cutting
// same-address collision chains ~8x. R10's cold-dispatch counters showed
// ~32 B HBM write traffic PER atomicAdd (48.6 MB for 1.57M atomics ->
// device-scope atomics execute at the chip coherence point), and runtime
// across R4-R10 fits latency-bound on that path (time ~ 1/resident-waves).
__global__ __launch_bounds__(256) void pairvel_mfma_kernel(
    const float* __restrict__ rel,       // [N,N,3]
    const int*   __restrict__ tgt,       // [E]
    const int*   __restrict__ src,       // [E]
    const float* __restrict__ force,     // [N,6]
    const float* __restrict__ visc,
    const float* __restrict__ medianp,
    const float* __restrict__ contactp,
    const float* __restrict__ W1,        // [19,128]
    const float* __restrict__ b1,        // [128]
    const float* __restrict__ W2,        // [128,128]
    const float* __restrict__ b2,        // [128]
    const float* __restrict__ W3,        // [128,6]
    const float* __restrict__ b3,        // [6]
    float* __restrict__ wsp)             // [NCOPY][N,6] partials
{
    const int tid = threadIdx.x;
    const int w   = tid >> 6;     // wave 0..3
    const int l   = tid & 63;     // lane
    const int l15 = l & 15;
    const int lhi = l >> 4;       // 0..3

    float* __restrict__ outc = wsp + (size_t)(blockIdx.x & (NCOPY - 1)) * OUTSZ;

    // ---- weight fragments (B operand: lane l holds W[kt*32+lhi*8+r][n16+l15])
    bf16x8 w1f[2], w2f[4][2], w3f[4];
    #pragma unroll
    for (int nb = 0; nb < 2; ++nb) {
        const int n = (2 * w + nb) * 16 + l15;
        #pragma unroll
        for (int r = 0; r < 8; ++r) {
            const int k = lhi * 8 + r;
            w1f[nb][r] = (k < 19) ? (__bf16)W1[k * HID + n] : (__bf16)0.0f;
        }
    }
    #pragma unroll
    for (int kt = 0; kt < 4; ++kt)
        #pragma unroll
        for (int nb = 0; nb < 2; ++nb) {
            const int n = (2 * w + nb) * 16 + l15;
            #pragma unroll
            for (int r = 0; r < 8; ++r)
                w2f[kt][nb][r] = (__bf16)W2[(kt * 32 + lhi * 8 + r) * HID + n];
        }
    #pragma unroll
    for (int kt = 0; kt < 4; ++kt)
        #pragma unroll
        for (int r = 0; r < 8; ++r) {
            const int k = kt * 32 + lhi * 8 + r;
            w3f[kt][r] = (l15 < FDOF) ? (__bf16)W3[k * FDOF + l15] : (__bf16)0.0f;
        }

    const float b1v0 = b1[(2 * w) * 16 + l15];
    const float b1v1 = b1[(2 * w + 1) * 16 + l15];
    const float b2v0 = b2[(2 * w) * 16 + l15];
    const float b2v1 = b2[(2 * w + 1) * 16 + l15];
    const float b3v  = (l15 < FDOF) ? b3[l15] : 0.0f;
    const float inv_mu  = 1.0f / visc[0];
    const float median  = medianp[0];
    const float contact = contactp[0];

    __shared__ __align__(16) __bf16 Xs[2][BM][XPAD];   // 10240 B
    __shared__ __align__(16) __bf16 Hs[BM][HPAD];      // 17408 B (H1 then H2)
    __shared__ int tgts[2][BM];                        //   512 B

    // zero X pad cols 19..31 in both buffers once
    for (int t = tid; t < 2 * BM * 13; t += 256) {
        const int b = t / (BM * 13), rem = t % (BM * 13);
        Xs[b][rem / 13][19 + rem % 13] = (__bf16)0.0f;
    }

    // ---- per-thread prefetch state (8 scalars) -----------------------------
    int   p_i0 = 0;
    float p_v0 = 0.f, p_v1 = 0.f, p_v2 = 0.f;
    float p_f3 = 0.f, p_f4 = 0.f, p_f5 = 0.f;

    auto gather_load = [&](int e0n) {
        if (tid < BM) {
            const int eg = e0n + tid;
            p_i0 = tgt[eg];
            const int sg = src[eg];
            const float* rp = rel + ((size_t)p_i0 * NPART + sg) * 3;
            p_v0 = rp[0]; p_v1 = rp[1]; p_v2 = rp[2];
        } else if (tid < 2 * BM) {
            const int eg = e0n + (tid - BM);
            const float2* f2 =
                reinterpret_cast<const float2*>(force + (size_t)tgt[eg] * FDOF);
            const float2 u0 = f2[0], u1 = f2[1], u2 = f2[2];
            p_v0 = u0.x; p_v1 = u0.y; p_v2 = u1.x;
            p_f3 = u1.y; p_f4 = u2.x; p_f5 = u2.y;
        } else if (tid < 3 * BM) {
            const int eg = e0n + (tid - 2 * BM);
            const float2* f2 =
                reinterpret_cast<const float2*>(force + (size_t)src[eg] * FDOF);
            const float2 u0 = f2[0], u1 = f2[1], u2 = f2[2];
            p_v0 = u0.x; p_v1 = u0.y; p_v2 = u1.x;
            p_f3 = u1.y; p_f4 = u2.x; p_f5 = u2.y;
        }
    };

    auto write_x = [&](int b) {
        if (tid < BM) {
            const int e = tid;
            tgts[b][e] = p_i0;
            const float dist = fmaxf(
                sqrtf(p_v0 * p_v0 + p_v1 * p_v1 + p_v2 * p_v2), 1e-8f);
            const float rs = (dist - median) * (dist - median);
            Xs[b][e][0] = (__bf16)p_v0;
            Xs[b][e][1] = (__bf16)p_v1;
            Xs[b][e][2] = (__bf16)p_v2;
            Xs[b][e][3] = (__bf16)dist;
            Xs[b][e][4] = (__bf16)rs;
            Xs[b][e][5] = (__bf16)(rs * rs);
            Xs[b][e][6] = (__bf16)(dist - contact);
        } else if (tid < 2 * BM) {
            const int e = tid - BM;
            Xs[b][e][7]  = (__bf16)p_v0;
            Xs[b][e][8]  = (__bf16)p_v1;
            Xs[b][e][9]  = (__bf16)p_v2;
            Xs[b][e][10] = (__bf16)p_f3;
            Xs[b][e][11] = (__bf16)p_f4;
            Xs[b][e][12] = (__bf16)p_f5;
        } else if (tid < 3 * BM) {
            const int e = tid - 2 * BM;
            Xs[b][e][13] = (__bf16)p_v0;
            Xs[b][e][14] = (__bf16)p_v1;
            Xs[b][e][15] = (__bf16)p_v2;
            Xs[b][e][16] = (__bf16)p_f3;
            Xs[b][e][17] = (__bf16)p_f4;
            Xs[b][e][18] = (__bf16)p_f5;
        }
    };

    // ---- prologue: stage iter-0 tile; issue iter-1 loads -------------------
    gather_load(blockIdx.x * BM);
    write_x(0);
    if (blockIdx.x + GRID < NIT) gather_load((blockIdx.x + GRID) * BM);
    int buf = 0;

    for (int it = blockIdx.x; it < NIT; it += GRID) {
        __syncthreads();   // (A) Xs[buf]/tgts[buf] staged; Hs free (L3 done)

        // ---- layer 1: H1 = relu(X @ W1 + b1) -> Hs -------------------------
        #pragma unroll
        for (int m = 0; m < 4; ++m) {
            const bf16x8 a = *reinterpret_cast<const bf16x8*>(
                &Xs[buf][m * 16 + l15][lhi * 8]);
            #pragma unroll
            for (int nb = 0; nb < 2; ++nb) {
                const float bv = nb ? b1v1 : b1v0;
                f32x4 acc = { bv, bv, bv, bv };
                acc = __builtin_amdgcn_mfma_f32_16x16x32_bf16(
                          a, w1f[nb], acc, 0, 0, 0);
                #pragma unroll
                for (int r = 0; r < 4; ++r)
                    Hs[m * 16 + lhi * 4 + r][(2 * w + nb) * 16 + l15] =
                        (__bf16)fmaxf(acc[r], 0.0f);
            }
        }
        __syncthreads();   // (B) H1 ready

        // ---- layer 2: accs = H1 @ W2 + b2 (registers only) -----------------
        f32x4 accs[4][2];
        #pragma unroll
        for (int m = 0; m < 4; ++m) {
            accs[m][0] = (f32x4){ b2v0, b2v0, b2v0, b2v0 };
            accs[m][1] = (f32x4){ b2v1, b2v1, b2v1, b2v1 };
            #pragma unroll
            for (int kt = 0; kt < 4; ++kt) {
                const bf16x8 a = *reinterpret_cast<const bf16x8*>(
                    &Hs[m * 16 + l15][kt * 32 + lhi * 8]);
                accs[m][0] = __builtin_amdgcn_mfma_f32_16x16x32_bf16(
                                 a, w2f[kt][0], accs[m][0], 0, 0, 0);
                accs[m][1] = __builtin_amdgcn_mfma_f32_16x16x32_bf16(
                                 a, w2f[kt][1], accs[m][1], 0, 0, 0);
            }
        }
        __syncthreads();   // (C) all H1 reads done -> Hs reusable

        // ---- write H2 into Hs; stage next X; issue next-next gather --------
        #pragma unroll
        for (int m = 0; m < 4; ++m)
            #pragma unroll
            for (int nb = 0; nb < 2; ++nb)
                #pragma unroll
                for (int r = 0; r < 4; ++r)
                    Hs[m * 16 + lhi * 4 + r][(2 * w + nb) * 16 + l15] =
                        (__bf16)fmaxf(accs[m][nb][r], 0.0f);

        if (it + GRID < NIT) write_x(buf ^ 1);          // consume prefetch regs
        if (it + 2 * GRID < NIT)
            gather_load((it + 2 * GRID) * BM);           // issue depth-2 loads
        __syncthreads();   // (D) H2 ready; Xs[buf^1] staged

        // ---- layer 3: vel = (H2 @ W3 + b3)/mu; wave w -> edges 16w..16w+15 -
        f32x4 acc3 = { 0.0f, 0.0f, 0.0f, 0.0f };
        #pragma unroll
        for (int kt = 0; kt < 4; ++kt) {
            const bf16x8 a = *reinterpret_cast<const bf16x8*>(
                &Hs[w * 16 + l15][kt * 32 + lhi * 8]);
            acc3 = __builtin_amdgcn_mfma_f32_16x16x32_bf16(
                       a, w3f[kt], acc3, 0, 0, 0);
        }
        if (l15 < FDOF) {
            #pragma unroll
            for (int r = 0; r < 4; ++r) {
                const int e = w * 16 + lhi * 4 + r;
                atomicAdd(&outc[(size_t)tgts[buf][e] * FDOF + l15],
                          (acc3[r] + b3v) * inv_mu);
            }
        }
        buf ^= 1;
    }
}

extern "C" void kernel_launch(void* const* d_in, const int* in_sizes, int n_in,
                              void* d_out, int out_size, void* d_ws, size_t ws_size,
                              hipStream_t stream) {
    const float* rel   = (const float*)d_in[0];
    const int*   tgt   = (const int*)d_in[1];
    const int*   src   = (const int*)d_in[2];
    const float* force = (const float*)d_in[3];
    const float* visc  = (const float*)d_in[4];
    const float* med   = (const float*)d_in[5];
    const float* con   = (const float*)d_in[6];
    const float* W1    = (const float*)d_in[7];
    const float* b1    = (const float*)d_in[8];
    const float* W2    = (const float*)d_in[9];
    const float* b2    = (const float*)d_in[10];
    const float* W3    = (const float*)d_in[11];
    const float* b3    = (const float*)d_in[12];
    float* out = (float*)d_out;
    float* wsp = (float*)d_ws;

    const int nws = NCOPY * OUTSZ;
    pairvel_zero_kernel<<<(nws + 255) / 256, 256, 0, stream>>>(wsp, nws);
    pairvel_mfma_kernel<<<GRID, 256, 0, stream>>>(
        rel, tgt, src, force, visc, med, con, W1, b1, W2, b2, W3, b3, wsp);
    pairvel_reduce_kernel<<<(OUTSZ + 255) / 256, 256, 0, stream>>>(wsp, out);
}